// Round 7
// baseline (61.278 us; speedup 1.0000x reference)
//
#include <hip/hip_runtime.h>

typedef __attribute__((ext_vector_type(8))) short short8;
typedef __attribute__((ext_vector_type(4))) float f32x4;
typedef __attribute__((ext_vector_type(4))) unsigned int u32x4;

#define NS    100000
#define DIM   128
#define BATCH 32
#define SEQ   20
#define NBLK  782              /* ceil(100000 / 128) */
#define NCH   25               /* stats chunks per batch row */

__device__ __forceinline__ unsigned int f2bf(float f) {
    unsigned int u = __float_as_uint(f);
    unsigned int r = u + 0x7FFFu + ((u >> 16) & 1u);
    return r >> 16;
}

// K1: normalize pred rows -> bf16 predp[b][32 rows][128]; rows 0..19 only.
__global__ __launch_bounds__(64) void k_prednorm(const float* __restrict__ pred,
                                                 unsigned short* __restrict__ predp) {
    int s = blockIdx.x, b = blockIdx.y;    // grid (20, 32)
    int lane = threadIdx.x;
    float2 v = ((const float2*)(pred + (size_t)(b * SEQ + s) * DIM))[lane];
    float ss = v.x * v.x + v.y * v.y;
    #pragma unroll
    for (int d = 1; d < 64; d <<= 1) ss += __shfl_xor(ss, d);
    float sc = 1.0f / fmaxf(sqrtf(ss), 1e-8f);
    unsigned int val = f2bf(v.x * sc) | (f2bf(v.y * sc) << 16);
    ((unsigned int*)(predp + ((size_t)b * 32 + s) * DIM))[lane] = val;
}

// K2: lean GEMM. 8 waves x 4 b's = 32 b per block; 128 songs/block.
// __launch_bounds__(512,2): 256-VGPR budget -> A-frags + accs fully resident.
__global__ __launch_bounds__(512, 2) void k_gemm(const float* __restrict__ song,
                                                 const unsigned short* __restrict__ predp,
                                                 float* __restrict__ sim) {
    const int tid  = threadIdx.x;
    const int lane = tid & 63;
    const int wid  = tid >> 6;          // 0..7
    const int l16  = lane & 15;
    const int g    = lane >> 4;         // 0..3
    const int song0 = blockIdx.x * 128;
    const int bq    = wid * 4;

    __shared__ u32x4 lds_[2048];        // 32 KB: [row 0..127][16 slots x 16B]
    char* const lds = (char*)lds_;

    // ---- phase 1: stage songs (keeps only 32+1 VGPRs live) ----
    {
        int gn = song0 + wid * 16 + l16;
        gn = gn < NS ? gn : NS - 1;
        const float* sp = song + (size_t)gn * DIM + g * 8;
        float4 v0[4], v1[4];
        #pragma unroll
        for (int kt = 0; kt < 4; ++kt) {
            v0[kt] = *(const float4*)(sp + kt * 32);
            v1[kt] = *(const float4*)(sp + kt * 32 + 4);
        }
        float ss = 0.f;
        #pragma unroll
        for (int kt = 0; kt < 4; ++kt) {
            ss += v0[kt].x*v0[kt].x + v0[kt].y*v0[kt].y + v0[kt].z*v0[kt].z + v0[kt].w*v0[kt].w;
            ss += v1[kt].x*v1[kt].x + v1[kt].y*v1[kt].y + v1[kt].z*v1[kt].z + v1[kt].w*v1[kt].w;
        }
        ss += __shfl_xor(ss, 16); ss += __shfl_xor(ss, 32);
        float sc = 1.0f / fmaxf(sqrtf(ss), 1e-8f);
        int row = wid * 16 + l16;       // row&7 == l16&7
        #pragma unroll
        for (int kt = 0; kt < 4; ++kt) {
            u32x4 o;
            o[0] = f2bf(v0[kt].x * sc) | (f2bf(v0[kt].y * sc) << 16);
            o[1] = f2bf(v0[kt].z * sc) | (f2bf(v0[kt].w * sc) << 16);
            o[2] = f2bf(v1[kt].x * sc) | (f2bf(v1[kt].y * sc) << 16);
            o[3] = f2bf(v1[kt].z * sc) | (f2bf(v1[kt].w * sc) << 16);
            *(u32x4*)(lds + row * 256 + (((kt * 4 + g) ^ (row & 7)) << 4)) = o;
        }
    }

    // ---- phase 2: A fragments (L2-hot; song regs are dead now) ----
    short8 Am[4][4];                    // [b_local][kt] rows 0..15
    short8 At[4];                       // packed tail: row l16 -> b=bq+(l16>>2), s=16+(l16&3)
    #pragma unroll
    for (int bl = 0; bl < 4; ++bl)
        #pragma unroll
        for (int kt = 0; kt < 4; ++kt)
            Am[bl][kt] = *(const short8*)(predp + ((size_t)(bq + bl) * 32 + l16) * DIM + kt * 32 + g * 8);
    {
        int tb = bq + (l16 >> 2), ts = 16 + (l16 & 3);
        #pragma unroll
        for (int kt = 0; kt < 4; ++kt)
            At[kt] = *(const short8*)(predp + ((size_t)tb * 32 + ts) * DIM + kt * 32 + g * 8);
    }
    __syncthreads();                    // the ONLY barrier

    // ---- free-running main loop: 4 chunks of 32 songs ----
    #pragma unroll 1
    for (int ch = 0; ch < 4; ++ch) {
        const char* r0 = lds + (ch * 32 + l16) * 256;
        const char* r1 = r0 + 16 * 256;
        short8 B0[4], B1[4];
        #pragma unroll
        for (int kt = 0; kt < 4; ++kt) {
            int po = (((kt * 4 + g) ^ (l16 & 7)) << 4);
            B0[kt] = *(const short8*)(r0 + po);
            B1[kt] = *(const short8*)(r1 + po);
        }
        f32x4 aM[4][2];
        f32x4 aT0 = {0,0,0,0}, aT1 = {0,0,0,0};
        #pragma unroll
        for (int bl = 0; bl < 4; ++bl) { aM[bl][0] = (f32x4){0,0,0,0}; aM[bl][1] = (f32x4){0,0,0,0}; }
        #pragma unroll
        for (int kt = 0; kt < 4; ++kt) {
            #pragma unroll
            for (int bl = 0; bl < 4; ++bl) {
                aM[bl][0] = __builtin_amdgcn_mfma_f32_16x16x32_bf16(Am[bl][kt], B0[kt], aM[bl][0], 0, 0, 0);
                aM[bl][1] = __builtin_amdgcn_mfma_f32_16x16x32_bf16(Am[bl][kt], B1[kt], aM[bl][1], 0, 0, 0);
            }
            aT0 = __builtin_amdgcn_mfma_f32_16x16x32_bf16(At[kt], B0[kt], aT0, 0, 0, 0);
            aT1 = __builtin_amdgcn_mfma_f32_16x16x32_bf16(At[kt], B1[kt], aT1, 0, 0, 0);
        }
        // ---- epilogue: per-b max over 20 rows -> masked coalesced store ----
        int n = song0 + ch * 32 + (lane & 31);
        bool do_st = (lane < 32) && (n < NS);
        float mt0 = fmaxf(fmaxf(aT0[0], aT0[1]), fmaxf(aT0[2], aT0[3]));
        float mt1 = fmaxf(fmaxf(aT1[0], aT1[1]), fmaxf(aT1[2], aT1[3]));
        #pragma unroll
        for (int bl = 0; bl < 4; ++bl) {
            float m0 = fmaxf(fmaxf(aM[bl][0][0], aM[bl][0][1]), fmaxf(aM[bl][0][2], aM[bl][0][3]));
            float m1 = fmaxf(fmaxf(aM[bl][1][0], aM[bl][1][1]), fmaxf(aM[bl][1][2], aM[bl][1][3]));
            m0 = (g == bl) ? fmaxf(m0, mt0) : m0;    // tail rows of b=bq+bl live in g==bl
            m1 = (g == bl) ? fmaxf(m1, mt1) : m1;
            m0 = fmaxf(m0, __shfl_xor(m0, 16)); m0 = fmaxf(m0, __shfl_xor(m0, 32));
            m1 = fmaxf(m1, __shfl_xor(m1, 16)); m1 = fmaxf(m1, __shfl_xor(m1, 32));
            float mo = (lane & 16) ? m1 : m0;
            if (do_st) sim[(size_t)(bq + bl) * NS + n] = mo;
        }
    }
}

// K3: streaming pass: Z = sum e^{s*x}, Y = sum e^y, U = sum e^{s*x+y}
__global__ __launch_bounds__(256) void k_stats(const float* __restrict__ sim,
                                               const float* __restrict__ x_inv,
                                               const float* __restrict__ y,
                                               float* __restrict__ pZ,
                                               float* __restrict__ pY,
                                               float* __restrict__ pU) {
    int c = blockIdx.x, b = blockIdx.y;
    int tid = threadIdx.x;
    size_t base4 = (size_t)b * (NS / 4) + (size_t)c * 1000;
    const float4* s4 = (const float4*)sim + base4;
    const float4* x4 = (const float4*)x_inv + base4;
    const float4* y4 = (const float4*)y + base4;
    float z = 0.f, yy = 0.f, u = 0.f;
    for (int i = tid; i < 1000; i += 256) {
        float4 sv = s4[i], xv = x4[i], yv = y4[i];
        float e0 = __expf(sv.x * xv.x), e1 = __expf(sv.y * xv.y);
        float e2 = __expf(sv.z * xv.z), e3 = __expf(sv.w * xv.w);
        float f0 = __expf(yv.x), f1 = __expf(yv.y);
        float f2 = __expf(yv.z), f3 = __expf(yv.w);
        z  += (e0 + e1) + (e2 + e3);
        yy += (f0 + f1) + (f2 + f3);
        u  += (e0 * f0 + e1 * f1) + (e2 * f2 + e3 * f3);
    }
    #pragma unroll
    for (int d = 1; d < 64; d <<= 1) {
        z += __shfl_xor(z, d); yy += __shfl_xor(yy, d); u += __shfl_xor(u, d);
    }
    __shared__ float sz[4], sy[4], su[4];
    int w = tid >> 6;
    if ((tid & 63) == 0) { sz[w] = z; sy[w] = yy; su[w] = u; }
    __syncthreads();
    if (tid == 0) {
        int o = b * NCH + c;
        pZ[o] = sz[0] + sz[1] + sz[2] + sz[3];
        pY[o] = sy[0] + sy[1] + sy[2] + sy[3];
        pU[o] = su[0] + su[1] + su[2] + su[3];
    }
}

// K4: combine 800 partials -> per-b loss -> mean
__global__ __launch_bounds__(1024) void k_finish(const float* __restrict__ pZ,
                                                 const float* __restrict__ pY,
                                                 const float* __restrict__ pU,
                                                 float* __restrict__ out) {
    __shared__ float sZ[BATCH * NCH], sY[BATCH * NCH], sU[BATCH * NCH], lb[BATCH];
    int tid = threadIdx.x;
    if (tid < BATCH * NCH) { sZ[tid] = pZ[tid]; sY[tid] = pY[tid]; sU[tid] = pU[tid]; }
    __syncthreads();
    if (tid < BATCH) {
        float Z = 0.f, Y = 0.f, U = 0.f;
        #pragma unroll
        for (int j = 0; j < NCH; ++j) {
            Z += sZ[tid * NCH + j]; Y += sY[tid * NCH + j]; U += sU[tid * NCH + j];
        }
        lb[tid] = logf((float)(NS + 1)) - U / (Y * Z);
    }
    __syncthreads();
    if (tid < 64) {
        float v = (tid < BATCH) ? lb[tid] : 0.f;
        #pragma unroll
        for (int d = 1; d < 64; d <<= 1) v += __shfl_xor(v, d);
        if (tid == 0) out[0] = v * (1.0f / BATCH);
    }
}

extern "C" void kernel_launch(void* const* d_in, const int* in_sizes, int n_in,
                              void* d_out, int out_size, void* d_ws, size_t ws_size,
                              hipStream_t stream) {
    const float* pred  = (const float*)d_in[0];
    const float* song  = (const float*)d_in[1];
    const float* x_inv = (const float*)d_in[2];
    const float* y     = (const float*)d_in[3];
    float* out = (float*)d_out;

    char* ws = (char*)d_ws;
    unsigned short* predp = (unsigned short*)ws;                   // 256 KiB
    float* sim = (float*)(ws + 262144);                            // 12.8 MB
    float* pZ  = (float*)(ws + 262144 + 12800000);                 // 800 f
    float* pY  = pZ + BATCH * NCH;
    float* pU  = pY + BATCH * NCH;

    k_prednorm<<<dim3(SEQ, BATCH), 64, 0, stream>>>(pred, predp);
    k_gemm<<<NBLK, 512, 0, stream>>>(song, predp, sim);
    k_stats<<<dim3(NCH, BATCH), 256, 0, stream>>>(sim, x_inv, y, pZ, pY, pU);
    k_finish<<<1, 1024, 0, stream>>>(pZ, pY, pU, out);
}